// Round 6
// baseline (100.247 us; speedup 1.0000x reference)
//
#include <hip/hip_runtime.h>
#include <stdint.h>

#define NROWS 8192
#define KDIM  512                           // k elems (= bytes in fp8) per row
#define BM    256                           // full tile edge
#define BK    128                           // R16: k-bytes per stage (was 64)
#define NKI   (KDIM / BK)                   // 4 K-iters
#define NT    (NROWS / BM)                  // 32 tiles per dim
#define NBLK  (NT * (NT + 1) / 2)           // 528 upper-tri tiles
#define NFULL 512                           // tiles 0..511 as full blocks
#define NTAIL (NBLK - NFULL)                // 16 tiles as 2x M-halves each
#define NTOTAL (NFULL + 2 * NTAIL)          // 544 completion-counter target

typedef __attribute__((ext_vector_type(4)))  int   i32x4;
typedef __attribute__((ext_vector_type(8)))  int   i32x8;
typedef __attribute__((ext_vector_type(16))) float f32x16;

__device__ __forceinline__ void async_copy16(const unsigned char* g, unsigned char* l) {
  __builtin_amdgcn_global_load_lds(
      (const __attribute__((address_space(1))) unsigned int*)g,
      (__attribute__((address_space(3))) unsigned int*)l,
      16, 0, 0);
}

// Kernel 1: row-normalize fp32 -> fp8 e4m3 (RNE), one wave per row.
// R16 PRE-SWIZZLE = R12's BK=128 scheme (verified absmax 0 in R12): the row
// is 4 windows of 128B (8 chunks of 16B). Within window, logical chunk c
// stored at slot p = c ^ (row & 7); halves inside chunks natural order.
// Bank math at 128B LDS row stride: bank = (row*32 + slot*4 + word)&31 --
// row drops out; per 16-lane ds_read_b128 phase the XOR spreads 16 rows
// over 8 slots x 4 words = 32 banks, 2-way aliasing = free (m136).
__global__ __launch_bounds__(256) void prep_kernel(
    const float* __restrict__ src, unsigned char* __restrict__ dst,
    float* __restrict__ acc) {
  const int row  = blockIdx.x * 4 + (threadIdx.x >> 6);
  const int lane = threadIdx.x & 63;
  const float4 v0 = ((const float4*)src)[row * 128 + lane * 2];
  const float4 v1 = ((const float4*)src)[row * 128 + lane * 2 + 1];
  float ss = v0.x * v0.x + v0.y * v0.y + v0.z * v0.z + v0.w * v0.w
           + v1.x * v1.x + v1.y * v1.y + v1.z * v1.z + v1.w * v1.w;
  #pragma unroll
  for (int off = 32; off > 0; off >>= 1) ss += __shfl_down(ss, off);
  const float rn = 1.0f / sqrtf(__shfl(ss, 0));   // norms ~22.6, EPS never fires
  if (row == 0 && lane == 0) { acc[0] = 0.0f; ((unsigned int*)acc)[1] = 0u; }
  int pk0 = __builtin_amdgcn_cvt_pk_fp8_f32(v0.x * rn, v0.y * rn, 0, false);
  pk0     = __builtin_amdgcn_cvt_pk_fp8_f32(v0.z * rn, v0.w * rn, pk0, true);
  int pk1 = __builtin_amdgcn_cvt_pk_fp8_f32(v1.x * rn, v1.y * rn, 0, false);
  pk1     = __builtin_amdgcn_cvt_pk_fp8_f32(v1.z * rn, v1.w * rn, pk1, true);
  const int cg  = lane >> 1;                        // chunk in row (0..31)
  const int win = cg >> 3;                          // 128B window (0..3)
  const int p   = (cg & 7) ^ (row & 7);             // R12 swizzle (verified)
  const int hf  = lane & 1;                         // natural half order
  uint2 o; o.x = (unsigned int)pk0; o.y = (unsigned int)pk1;
  ((uint2*)dst)[row * 64 + win * 16 + p * 2 + hf] = o;  // 128B window = 16 uint2
}

__device__ __forceinline__ int tri_base(int b) {   // # tiles before row b
  return b * NT - (b * (b - 1)) / 2;
}

// Kernel 2: fp8 MX-MFMA GEMM (idn @ idn^T) fused with clamp, diag mask,
// reduction, finalize (completion counter, target NTOTAL across BOTH grids).
// R16 theory: R12 (2x MFMA rate), R13 (1/2 traffic), R15 (makespan -18%)
// were ALL null within noise -> no throughput pipe is marginal; stage time
// is dominated by per-stage overhead (2 barriers + vmcnt drain + lockstep
// issue convoy at 1 block/CU). Lever: HALVE the stage count. BK 64->128,
// NKI 4: same bytes, same MFMAs, half the barrier/vmcnt events (sim<4>:
// 16 -> 8 serialized stage-units per CU). Recombines verified pieces:
// R13/R15 256-row geometry + R12 BK=128 swizzle/fragment addressing.
// MN is a template param (R15: runtime MN predication demoted acc_f to
// scratch -- 142 MB spill); two stream-ordered launches:
//   sim<4> x 512: full 256x256 tiles, exactly 2 rounds at 1 blk/CU
//   sim<2> x 32:  last 16 tiles as 128x256 M-halves, ~t/2 round
// K is NOT split (relu(sum) != sum(relu)); M-split keeps full-K dots exact.
// LDS: MN=4 -> 2x32 + 2x32 = 128 KB; MN=2 -> 96 KB. VGPR ~205 (<256, same
// 2 waves/SIMD occupancy as R15).
template <int MN>                      // 4 = full 256 rows, 2 = half 128 rows
__global__ __launch_bounds__(512, 2) void sim_reduce_kernel(
    const unsigned char* __restrict__ idn, float* __restrict__ acc,
    float* __restrict__ out) {
  constexpr int AROWS = MN * 64;       // staged A rows per block: 256 / 128
  constexpr int ACOP  = MN;            // A copies per thread per stage: 4 / 2

  const int idx  = (MN == 4) ? (int)blockIdx.x : NFULL + ((int)blockIdx.x >> 1);
  const int half = (MN == 4) ? 0 : ((int)blockIdx.x & 1);

  // triangular decode (block-uniform scalar math, R1-proven)
  const float Af = 2.0f * NT + 1.0f;
  int bi = (int)((Af - sqrtf(Af * Af - 8.0f * (float)idx)) * 0.5f);
  while (bi > 0 && tri_base(bi) > idx) bi--;
  while (tri_base(bi + 1) <= idx) bi++;
  const int bj = bi + (idx - tri_base(bi));

  __shared__ __align__(16) unsigned char As[2][AROWS * BK];  // 32 / 16 KB each
  __shared__ __align__(16) unsigned char Bs[2][BM * BK];     // 32 KB each

  const int tid  = threadIdx.x;      // 0..511, 8 waves
  const int lane = tid & 63;
  const int w    = tid >> 6;
  const int wrow = (w >> 2) * (MN * 32);   // wave row base in staged region
  const int wcol = (w & 3) * 64;
  const int r32  = lane & 31;        // row within 32-row MFMA tile
  const int h    = lane >> 5;        // k-half selector (k = h*32 + j)
  const int rx   = r32 & 7;          // chunk swizzle key (8-slot windows)

  f32x16 acc_f[MN][2];
  #pragma unroll
  for (int i = 0; i < MN; i++)
    #pragma unroll
    for (int j = 0; j < 2; j++)
      acc_f[i][j] = (f32x16){0.f, 0.f, 0.f, 0.f, 0.f, 0.f, 0.f, 0.f,
                             0.f, 0.f, 0.f, 0.f, 0.f, 0.f, 0.f, 0.f};

  // Staging: per stage AROWS*8 A-chunks + 2048 B-chunks of 16B; copy i,
  // thread t covers chunk i*512+t: row = i*64 + (t>>3), slot = t&7. LDS
  // dest lane-linear (chunk*16 = wave-uniform base + lane*16,
  // global_load_lds constraint); memory already holds the swizzled slot
  // order so staging is a straight 128B-window copy, 8 lanes per window.
  const unsigned char* gA =
      idn + (size_t)(bi * BM + half * 128 + (tid >> 3)) * KDIM + (tid & 7) * 16;
  const unsigned char* gB = idn + (size_t)(bj * BM + (tid >> 3)) * KDIM + (tid & 7) * 16;
  const int ldso = tid * 16;         // + i*8192 per copy group (i covers 64 rows)

  // prologue: stage 0 <- k-window 0
  #pragma unroll
  for (int i = 0; i < ACOP; i++) async_copy16(gA + (size_t)i * 32768, &As[0][ldso + i * 8192]);
  #pragma unroll
  for (int i = 0; i < 4; i++)    async_copy16(gB + (size_t)i * 32768, &Bs[0][ldso + i * 8192]);

  #pragma unroll
  for (int t = 0; t < NKI; ++t) {
    const int cs = t & 1;
    if (t + 1 < NKI) {
      const int ns = cs ^ 1;
      const int ko = (t + 1) * BK;
      #pragma unroll
      for (int i = 0; i < ACOP; i++)
        async_copy16(gA + ko + (size_t)i * 32768, &As[ns][ldso + i * 8192]);
      #pragma unroll
      for (int i = 0; i < 4; i++)
        async_copy16(gB + ko + (size_t)i * 32768, &Bs[ns][ldso + i * 8192]);
      // stage t's (ACOP+4) copies landed; stage t+1's (ACOP+4) stay in flight
      if constexpr (MN == 4) asm volatile("s_waitcnt vmcnt(8)" ::: "memory");
      else                   asm volatile("s_waitcnt vmcnt(6)" ::: "memory");
    } else {
      asm volatile("s_waitcnt vmcnt(0)" ::: "memory");
    }
    asm volatile("s_barrier" ::: "memory");   // all waves' stage-t fills visible

    // 2 k-slices (K=64 each) per BK=128 stage (R12-verified addressing).
    // Lane (r32,h), slice ks: logical chunks c0 = 4*ks + 2*h and c0+1 at
    // swizzled slots ^rx; each frag = 2x ds_read_b128, 2-way banks (free).
    #pragma unroll
    for (int ks = 0; ks < 2; ks++) {
      const int p0 = ((4 * ks + 2 * h)     ^ rx) * 16;
      const int p1 = ((4 * ks + 2 * h + 1) ^ rx) * 16;
      i32x8 af[MN], bf[2];
      #pragma unroll
      for (int ni = 0; ni < 2; ni++) {
        const unsigned char* bb = &Bs[cs][(wcol + ni * 32 + r32) * BK];
        const i32x4 blo = *(const i32x4*)(bb + p0);
        const i32x4 bhi = *(const i32x4*)(bb + p1);
        bf[ni] = __builtin_shufflevector(blo, bhi, 0, 1, 2, 3, 4, 5, 6, 7);
      }
      #pragma unroll
      for (int mi = 0; mi < MN; mi++) {
        const unsigned char* ab = &As[cs][(wrow + mi * 32 + r32) * BK];
        const i32x4 alo = *(const i32x4*)(ab + p0);
        const i32x4 ahi = *(const i32x4*)(ab + p1);
        af[mi] = __builtin_shufflevector(alo, ahi, 0, 1, 2, 3, 4, 5, 6, 7);
      }
      #pragma unroll
      for (int mi = 0; mi < MN; mi++)
        #pragma unroll
        for (int ni = 0; ni < 2; ni++)
          acc_f[mi][ni] = __builtin_amdgcn_mfma_scale_f32_32x32x64_f8f6f4(
              af[mi], bf[ni], acc_f[mi][ni],
              0, 0,                       // A fmt = fp8 e4m3, B fmt = fp8 e4m3
              0, 0x7F7F7F7Fu,             // A scale: E8M0 127 -> 1.0
              0, 0x7F7F7F7Fu);            // B scale: E8M0 127 -> 1.0
    }

    asm volatile("s_barrier" ::: "memory");   // compute(t) done before t+1 refill
  }

  // Epilogue: clamp at zero, mask diagonal, reduce.
  // C/D layout for 32x32 shapes (m74/m101; dtype-independent m121-m128):
  // col = lane&31, row = (reg&3) + 8*(reg>>2) + 4*(lane>>5). R12-R15 verified.
  float local = 0.f;
  const bool diag = (bi == bj);
  #pragma unroll
  for (int mi = 0; mi < MN; mi++)
    #pragma unroll
    for (int ni = 0; ni < 2; ni++)
      #pragma unroll
      for (int rg = 0; rg < 16; rg++) {
        const int ri = half * 128 + wrow + mi * 32 + (rg & 3) + 8 * (rg >> 2) + 4 * h;
        const int ci = wcol + ni * 32 + r32;
        float v = fmaxf(acc_f[mi][ni][rg], 0.f);
        if (diag && ri == ci) v = 0.f;
        local += v;
      }

  #pragma unroll
  for (int off = 32; off > 0; off >>= 1) local += __shfl_down(local, off);
  __syncthreads();                   // staging dead; reuse Bs for reduce
  float* red = (float*)Bs;
  if (lane == 0) red[w] = local;
  __syncthreads();
  if (tid == 0) {
    float s = red[0] + red[1] + red[2] + red[3]
            + red[4] + red[5] + red[6] + red[7];
    if (!diag) s *= 2.f;             // strictly-upper tiles cover both triangles
    atomicAdd(acc, s);
    // fused finalize: last-arriving block (across both grids) writes outputs.
    __threadfence();                               // acc-add visible before count
    unsigned int done = atomicAdd((unsigned int*)(acc + 1), 1u);
    if (done == NTOTAL - 1) {
      float total = atomicAdd(acc, 0.0f);          // device-scope RMW read
      const float m = total * (1.0f / ((float)NROWS * (float)NROWS));
      out[0] = m;
      out[1] = m;
    }
  }
}

extern "C" void kernel_launch(void* const* d_in, const int* in_sizes, int n_in,
                              void* d_out, int out_size, void* d_ws, size_t ws_size,
                              hipStream_t stream) {
  const float* id = (const float*)d_in[0];
  float* out = (float*)d_out;
  unsigned char* idn = (unsigned char*)d_ws;                       // 4 MB fp8
  float* acc = (float*)((char*)d_ws + (size_t)NROWS * KDIM);       // [0]=sum, [1]=counter

  prep_kernel<<<NROWS / 4, 256, 0, stream>>>(id, idn, acc);
  sim_reduce_kernel<4><<<NFULL, 512, 0, stream>>>(idn, acc, out);      // 2 full rounds
  sim_reduce_kernel<2><<<2 * NTAIL, 512, 0, stream>>>(idn, acc, out);  // ~t/2 tail
}